// Round 10
// baseline (28.327 us; speedup 1.0000x reference)
//
#include <hip/hip_runtime.h>

#define DD 128
#define HH 160
#define WW 128
#define BB 4
#define HW  20480
#define DHW 2621440

#define TX 32
#define TY 8
#define TZ 4
#define XT (WW / TX)             // 4
#define YT (HH / TY)             // 20
#define ZT (DD / TZ)             // 32
#define NWG (XT * YT * ZT * BB)  // 10240
#define NXCD 8
#define CPX (NWG / NXCD)         // 1280
#define LDSF 5120                // floats = 20.48 KB -> 7 blocks/CU, 28 waves
#define MAXCH (LDSF / 4)         // 1280 16B chunks

typedef float f2 __attribute__((ext_vector_type(2), aligned(4)));
typedef float v2 __attribute__((ext_vector_type(2)));

__global__ __launch_bounds__(256)
void st_affine_kernel(const float* __restrict__ src,
                      const float* __restrict__ aff,
                      float* __restrict__ out) {
    __shared__ float lds[LDSF];

    // XCD-aware bijective swizzle (NWG % 8 == 0)
    const int wgid = blockIdx.x;
    const int lin  = (wgid & (NXCD - 1)) * CPX + (wgid >> 3);
    const int xt = lin & 3;
    const int l2 = lin >> 2;
    const int yt = l2 % YT;
    const int l3 = l2 / YT;
    const int zt = l3 & 31;
    const int b  = l3 >> 5;
    const int x0t = xt * TX, y0t = yt * TY, z0t = zt * TZ;

    const float* A = aff + b * 12;   // uniform -> scalar loads
    const float cD = 128.f/127.f, cH = 160.f/159.f, cW = 128.f/127.f;
    const float pz0 = A[0]*cD, pz1 = A[1]*cD, pz2 = A[2]*cD,  pz3 = fmaf(A[3],  cD, -0.5f);
    const float py0 = A[4]*cH, py1 = A[5]*cH, py2 = A[6]*cH,  py3 = fmaf(A[7],  cH, -0.5f);
    const float px0 = A[8]*cW, px1 = A[9]*cW, px2 = A[10]*cW, px3 = fmaf(A[11], cW, -0.5f);

    // ---- bbox of a linear map over a box: center +- sum(|coef|*halfext) ----
    const float hz = (TZ - 1) * 0.5f, hy = (TY - 1) * 0.5f, hx = (TX - 1) * 0.5f;
    const float ccz = (float)z0t + hz, ccy = (float)y0t + hy, ccx = (float)x0t + hx;
    const float izcn = fmaf(pz0, ccz, fmaf(pz1, ccy, fmaf(pz2, ccx, pz3)));
    const float iycn = fmaf(py0, ccz, fmaf(py1, ccy, fmaf(py2, ccx, py3)));
    const float ixcn = fmaf(px0, ccz, fmaf(px1, ccy, fmaf(px2, ccx, px3)));
    const float rz = fmaf(fabsf(pz0), hz, fmaf(fabsf(pz1), hy, fmaf(fabsf(pz2), hx, 1e-3f)));
    const float ry = fmaf(fabsf(py0), hz, fmaf(fabsf(py1), hy, fmaf(fabsf(py2), hx, 1e-3f)));
    const float rx = fmaf(fabsf(px0), hz, fmaf(fabsf(px1), hy, fmaf(fabsf(px2), hx, 1e-3f)));
    const float mnz = izcn - rz, mxz = izcn + rz;
    const float mny = iycn - ry, mxy = iycn + ry;
    const float mnx = ixcn - rx, mxx = ixcn + rx;

    // interior: every sample strictly inside [0, S-1) -> all clamps are no-ops
    const bool interior =
        (mnz > 0.02f) && (mxz < 126.98f) &&
        (mny > 0.02f) && (mxy < 158.98f) &&
        (mnx > 0.02f) && (mxx < 126.98f);

    const int xlo = max(0, (int)floorf(__builtin_amdgcn_fmed3f(mnx, 0.f, 127.f)) - 1);
    const int ylo = max(0, (int)floorf(__builtin_amdgcn_fmed3f(mny, 0.f, 159.f)) - 1);
    const int zlo = max(0, (int)floorf(__builtin_amdgcn_fmed3f(mnz, 0.f, 127.f)) - 1);
    const int xhi = min(WW - 2, (int)floorf(__builtin_amdgcn_fmed3f(mxx, 0.f, 127.f)) + 1);
    const int yhi = min(HH - 2, (int)floorf(__builtin_amdgcn_fmed3f(mxy, 0.f, 159.f)) + 1);
    const int zhi = min(DD - 2, (int)floorf(__builtin_amdgcn_fmed3f(mxz, 0.f, 127.f)) + 1);

    const int xlo4  = xlo & ~3;
    const int XE4   = xhi - xlo4 + 2;
    const int YE    = yhi - ylo + 2;
    const int ZE    = zhi - zlo + 2;
    const int pitch = (XE4 + 3) & ~3;
    const int cpr   = pitch >> 2;
    const int slice = YE * pitch;
    const int totalChunks = ZE * YE * cpr;
    const bool fits = (totalChunks <= MAXCH);

    const int tid  = threadIdx.x;
    const int lane = tid & 63;
    const int wid  = tid >> 6;

    // ---- dense full-wave staging: chunk k -> (z,y,x-chunk) of bbox ----
    // per-chunk address clamp to DHW-4 makes the tail safe; clamped chunks
    // are provably never read by the compute phase (reads stay < W per row).
    if (fits) {
        const float rcpr = 1.f / (float)cpr, rYE = 1.f / (float)YE;
        const float cprF = (float)cpr, YEfS = (float)YE;
        const float zloF = (float)zlo, yloF = (float)ylo, xlo4F = (float)xlo4;
        const float* sb = src + b * DHW;
        const int nIt = (totalChunks + 255) >> 8;     // <= 5
        for (int it = 0; it < nIt; ++it) {
            const int k = (it << 8) + tid;            // overshoot lands in
            float kf   = (float)k;                    // unused LDS (clamped)
            float rowf = floorf(fmaf(kf, rcpr, 0.5f * rcpr));   // k / cpr
            float xif  = fmaf(-rowf, cprF, kf);                 // k % cpr
            float zif  = floorf(fmaf(rowf, rYE, 0.5f * rYE));   // row / YE
            float yif  = fmaf(-zif, YEfS, rowf);                // row % YE
            float gf   = fmaf(zloF + zif, 20480.f,
                         fmaf(yloF + yif, 128.f,
                         fmaf(xif, 4.f, xlo4F)));     // exact in fp32 (<2^23)
            int g = min((int)gf, DHW - 4);
            __builtin_amdgcn_global_load_lds(
                (const __attribute__((address_space(1))) void*)(sb + g),
                (__attribute__((address_space(3))) void*)(lds + (size_t)(((it << 8) + (wid << 6)) * 4)),
                16, 0, 0);
        }
    }
    __syncthreads();

    // ---- outputs: x-pair x 2 z per thread (tile 32x8x4, 1024 outputs) ----
    const int xp = x0t + ((lane & 15) << 1);
    const int yo = y0t + (lane >> 4) + ((wid & 1) << 2);
    const int zb = z0t + ((wid >> 1) << 1);
    const float fx0 = (float)xp, fy = (float)yo, fzb = (float)zb;

    const float izb0 = fmaf(pz0, fzb, fmaf(pz1, fy, fmaf(pz2, fx0, pz3)));
    const float iyb0 = fmaf(py0, fzb, fmaf(py1, fy, fmaf(py2, fx0, py3)));
    const float ixb0 = fmaf(px0, fzb, fmaf(px1, fy, fmaf(px2, fx0, px3)));
    const float izb1 = izb0 + pz2, iyb1 = iyb0 + py2, ixb1 = ixb0 + px2;

    const float zloF = (float)zlo, yloF = (float)ylo, xlo4F = (float)xlo4;
    const float YEf = (float)YE, pitchF = (float)pitch;
    float* dst = out + (size_t)(((b * DD + zb) * HH + yo) * WW + xp);

    auto lerpL = [&](int o, float wxs, float wys, float wzs) -> float {
        f2 v00 = *(const f2*)(lds + o);
        f2 v01 = *(const f2*)(lds + o + pitch);
        f2 v10 = *(const f2*)(lds + o + slice);
        f2 v11 = *(const f2*)(lds + o + slice + pitch);
        float c00 = fmaf(v00.y - v00.x, wxs, v00.x);
        float c01 = fmaf(v01.y - v01.x, wxs, v01.x);
        float c10 = fmaf(v10.y - v10.x, wxs, v10.x);
        float c11 = fmaf(v11.y - v11.x, wxs, v11.x);
        float c0 = fmaf(c01 - c00, wys, c00);
        float c1 = fmaf(c11 - c10, wys, c10);
        return fmaf(c1 - c0, wzs, c0);
    };
    auto lerpG = [&](float cz, float cy, float cx, float wxs, float wys, float wzs) -> float {
        int o = (int)fmaf(cz, 20480.f, fmaf(cy, 128.f, cx));
        const float* p = src + b * DHW + o;
        f2 v00 = *(const f2*)(p);
        f2 v01 = *(const f2*)(p + WW);
        f2 v10 = *(const f2*)(p + HW);
        f2 v11 = *(const f2*)(p + HW + WW);
        float c00 = fmaf(v00.y - v00.x, wxs, v00.x);
        float c01 = fmaf(v01.y - v01.x, wxs, v01.x);
        float c10 = fmaf(v10.y - v10.x, wxs, v10.x);
        float c11 = fmaf(v11.y - v11.x, wxs, v11.x);
        float c0 = fmaf(c01 - c00, wys, c00);
        float c1 = fmaf(c11 - c10, wys, c10);
        return fmaf(c1 - c0, wzs, c0);
    };

#pragma unroll
    for (int kq = 0; kq < 2; ++kq) {
        const float kf = (float)kq;
        float iz0 = fmaf(kf, pz0, izb0), iz1 = fmaf(kf, pz0, izb1);
        float iy0 = fmaf(kf, py0, iyb0), iy1 = fmaf(kf, py0, iyb1);
        float ix0 = fmaf(kf, px0, ixb0), ix1 = fmaf(kf, px0, ixb1);
        float cz0, cy0, cx0, cz1, cy1, cx1;
        if (interior) {
            cz0 = floorf(iz0); cz1 = floorf(iz1);
            cy0 = floorf(iy0); cy1 = floorf(iy1);
            cx0 = floorf(ix0); cx1 = floorf(ix1);
        } else {
            iz0 = __builtin_amdgcn_fmed3f(iz0, 0.f, 127.f);
            iz1 = __builtin_amdgcn_fmed3f(iz1, 0.f, 127.f);
            iy0 = __builtin_amdgcn_fmed3f(iy0, 0.f, 159.f);
            iy1 = __builtin_amdgcn_fmed3f(iy1, 0.f, 159.f);
            ix0 = __builtin_amdgcn_fmed3f(ix0, 0.f, 127.f);
            ix1 = __builtin_amdgcn_fmed3f(ix1, 0.f, 127.f);
            cz0 = fminf(floorf(iz0), 126.f); cz1 = fminf(floorf(iz1), 126.f);
            cy0 = fminf(floorf(iy0), 158.f); cy1 = fminf(floorf(iy1), 158.f);
            cx0 = fminf(floorf(ix0), 126.f); cx1 = fminf(floorf(ix1), 126.f);
        }
        const float wz0 = iz0 - cz0, wz1 = iz1 - cz1;
        const float wy0 = iy0 - cy0, wy1 = iy1 - cy1;
        const float wx0 = ix0 - cx0, wx1 = ix1 - cx1;

        v2 r;
        if (fits) {
            int o0 = (int)fmaf(fmaf(cz0 - zloF, YEf, cy0 - yloF), pitchF, cx0 - xlo4F);
            int o1 = (int)fmaf(fmaf(cz1 - zloF, YEf, cy1 - yloF), pitchF, cx1 - xlo4F);
            r.x = lerpL(o0, wx0, wy0, wz0);
            r.y = lerpL(o1, wx1, wy1, wz1);
        } else {
            r.x = lerpG(cz0, cy0, cx0, wx0, wy0, wz0);
            r.y = lerpG(cz1, cy1, cx1, wx1, wy1, wz1);
        }
        __builtin_nontemporal_store(r, (v2*)(dst + kq * HW));
    }
}

extern "C" void kernel_launch(void* const* d_in, const int* in_sizes, int n_in,
                              void* d_out, int out_size, void* d_ws, size_t ws_size,
                              hipStream_t stream) {
    const float* src = (const float*)d_in[0];
    const float* aff = (const float*)d_in[1];
    float* out = (float*)d_out;

    st_affine_kernel<<<dim3(NWG), dim3(256), 0, stream>>>(src, aff, out);
}